// Round 6
// baseline (133.889 us; speedup 1.0000x reference)
//
#include <hip/hip_runtime.h>

// SNN forward: T=128, B=8192, I=2, H=256, O=2
//  cur[t,b,h] = x[t,b,0]*W1[h,0] + x[t,b,1]*W1[h,1]
//  scan: reset = (mem>1); mem = 0.9*mem + cur - reset; spk = (mem>1)
//  out[b,o] = (mean of spk over last 10 t) dot W2[o,:]
//
// R16 = scalar STEPP (R10's exact op sequence) x 8 waves/SIMD (R13's shape).
// Measured ladder (scan dispatch, busy = VALUBusy x dur):
//   R10 scalar RH=8, 4 w/SIMD ...... 51.4 us  busy 37.8  VALUBusy 73%
//   R11 pk-broadcast RH=8 .......... 51.5 us  busy 37.6  (instr -1.6x, time
//        flat -> fp32 pipe width/issue bound, pk buys nothing)
//   R12 fused threadfence reduce ... 75.2 us  (fence poison; REVERTED)
//   R13 pk-PAIR RH=4, 8 w/SIMD ..... 59.2 us  busy 49.7  VALUBusy 84%
//   R15 pk-PAIR RH=8, 4 w/SIMD ..... 59.9 us  busy 48.0  VALUBusy 80%
// R13 == R15 within noise -> the pk-PAIR STEPP (not RH) was the regression:
// marshaling cc.x/cc.y into even-aligned pairs for inline-asm pk_add costs
// ~2 movs/pair/step = the +10 us busy. REVERTED to scalar ops everywhere.
// R13 also proved 8 waves/SIMD lifts issue utilization 73 -> 84%.
// This round combines: scalar STEPP busy (37.8) / 0.84 ~= 45-48 us.
//
// Epilogue bit-exactness (absmax must stay 0.0): R13's verified scheme.
// Old tree: per-wave 8-term sequential __fadd_rn chain (ascending h), then
// (c0+c1)+(c2+c3) over 4 waves, then ascending-hg chain in snn_reduce.
// With RH=4 threads publish avg[h]=cnt/10 to LDS; wave0 rebuilds the EXACT
// chains: c_k = sequential 8-term chain over h_local=8k..8k+7,
// s = (c0+c1)+(c2+c3). partial layout + snn_reduce unchanged.
//
// Kept: saddr-form loads (t*BATCH wave-uniform SGPR base + fixed lane
// voffset, zero per-load VALU), PF=8 rotating register prefetch, XCD
// swizzle (bg=blockIdx&127, hg=blockIdx>>7), per-op fp32 rounding, no FMA.

#define T_STEPS 128
#define BATCH   8192
#define HID     256
#define TAIL    10
#define RH      4      // hidden chains per thread
#define LB      64     // batch rows per block (= lanes per wave)
#define NWAVE   8      // waves per block; block covers NWAVE*RH = 32 h
#define HG      8      // h-groups (HID / 32)
#define NBG     (BATCH / LB)   // 128 batch groups
#define PF      8      // prefetch depth (t-steps in flight)

__global__ __launch_bounds__(512, 8) void snn_scan(const float* __restrict__ x,
                                                   const float* __restrict__ W1,
                                                   const float* __restrict__ W2,
                                                   float2* __restrict__ partial) {
    const int tid   = threadIdx.x;
    const int lane  = tid & 63;
    const int wave  = tid >> 6;                // 0..7
    const int bg    = blockIdx.x & (NBG - 1);  // same bg -> same XCD for all hg
    const int hg    = blockIdx.x >> 7;         // 0..7
    const int b     = bg * LB + lane;          // batch row (lane part of addr)
    const int hbase = hg * (NWAVE * RH) + wave * RH;

    // W1 rows for my 4 h (wave-uniform addresses -> scalarized, one-time)
    float w0[RH], w1[RH];
#pragma unroll
    for (int r = 0; r < RH; ++r) {
        w0[r] = W1[2 * (hbase + r)];
        w1[r] = W1[2 * (hbase + r) + 1];
    }

    // Uniform-base addressing: xp + t*BATCH is wave-uniform (SGPR base,
    // SALU-stepped); + b is the fixed per-lane voffset.
    const float2* xp = (const float2*)x;

    float mem[RH], spk[RH], cnt[RH];
#pragma unroll
    for (int r = 0; r < RH; ++r) { mem[r] = 0.0f; spk[r] = 0.0f; cnt[r] = 0.0f; }

#define LOADX(t) xp[(size_t)(t) * BATCH + b]

    // R10's exact per-element op sequence (scalar, per-op rounding, no FMA):
#define STEP(r, xa, xc)                                                           \
    {                                                                             \
        const float c = __fadd_rn(__fmul_rn((xa), w0[r]), __fmul_rn((xc), w1[r]));\
        mem[r] = __fsub_rn(__fadd_rn(__fmul_rn(0.9f, mem[r]), c), spk[r]);        \
        spk[r] = (mem[r] > 1.0f) ? 1.0f : 0.0f;                                   \
    }

    // ---- warm-up: fill rotating prefetch buffer with t = 0..7 ----
    float2 buf[PF];
#pragma unroll
    for (int j = 0; j < PF; ++j) buf[j] = LOADX(j);

    // ---- main loop: t = 0..111 (14 iters), prefetch t+8 (<= 119) ----
    for (int tb = 0; tb < T_STEPS - 2 * PF; tb += PF) {
#pragma unroll
        for (int j = 0; j < PF; ++j) {
            const float2 xv = buf[j];
            buf[j] = LOADX(tb + PF + j);
#pragma unroll
            for (int r = 0; r < RH; ++r) STEP(r, xv.x, xv.y)
        }
    }

    // ---- t = 112..119: consume buf[j], refill with t = 120..127 ----
#pragma unroll
    for (int j = 0; j < PF; ++j) {
        const float2 xv = buf[j];
        buf[j] = LOADX(T_STEPS - PF + j);
#pragma unroll
        for (int r = 0; r < RH; ++r) {
            STEP(r, xv.x, xv.y)
            if (j >= PF - 2) cnt[r] += spk[r];   // t = 118, 119
        }
    }
    // ---- t = 120..127 (all counted) ----
#pragma unroll
    for (int j = 0; j < PF; ++j) {
        const float2 xv = buf[j];
#pragma unroll
        for (int r = 0; r < RH; ++r) {
            STEP(r, xv.x, xv.y)
            cnt[r] += spk[r];   // integer-valued, exact in fp32
        }
    }
#undef STEP
#undef LOADX

    // Publish per-h tail averages; wave0 rebuilds the exact R10 tree.
    __shared__ float avgs[NWAVE * RH][LB];    // 32 x 64 floats = 8 KB
#pragma unroll
    for (int r = 0; r < RH; ++r)
        avgs[wave * RH + r][lane] = cnt[r] / 10.0f;
    __syncthreads();

    if (wave == 0) {
        // c_k = sequential 8-term __fadd_rn chain over h_local = 8k..8k+7
        // (== old wave-k per-thread chain), then (c0+c1)+(c2+c3).
        float c0[4], c1[4];
#pragma unroll
        for (int k = 0; k < 4; ++k) {
            float s0 = 0.0f, s1 = 0.0f;
#pragma unroll
            for (int j = 0; j < 8; ++j) {
                const int hl = 8 * k + j;
                const float a = avgs[hl][lane];
                s0 = __fadd_rn(s0, __fmul_rn(a, W2[hg * 32 + hl]));
                s1 = __fadd_rn(s1, __fmul_rn(a, W2[HID + hg * 32 + hl]));
            }
            c0[k] = s0; c1[k] = s1;
        }
        float2 s;
        s.x = __fadd_rn(__fadd_rn(c0[0], c0[1]), __fadd_rn(c0[2], c0[3]));
        s.y = __fadd_rn(__fadd_rn(c1[0], c1[1]), __fadd_rn(c1[2], c1[3]));
        partial[(size_t)hg * BATCH + b] = s;
    }
}

// sum the 8 h-group partials -> out[b, 0:2] (ascending hg, exact chain)
__global__ __launch_bounds__(256) void snn_reduce(const float2* __restrict__ partial,
                                                  float2* __restrict__ out) {
    const int b = blockIdx.x * 256 + threadIdx.x;   // 8192 threads
    float sx = 0.0f, sy = 0.0f;
#pragma unroll
    for (int hg = 0; hg < HG; ++hg) {
        const float2 p = partial[(size_t)hg * BATCH + b];
        sx = __fadd_rn(sx, p.x);
        sy = __fadd_rn(sy, p.y);
    }
    out[b] = make_float2(sx, sy);
}

extern "C" void kernel_launch(void* const* d_in, const int* in_sizes, int n_in,
                              void* d_out, int out_size, void* d_ws, size_t ws_size,
                              hipStream_t stream) {
    const float* x  = (const float*)d_in[0];  // (128, 8192, 2)
    const float* W1 = (const float*)d_in[1];  // (256, 2)
    const float* W2 = (const float*)d_in[2];  // (2, 256)
    float2* out     = (float2*)d_out;         // (8192, 2)
    float2* partial = (float2*)d_ws;          // (8, 8192) float2 = 512 KB scratch

    snn_scan<<<NBG * HG, 512, 0, stream>>>(x, W1, W2, partial);
    snn_reduce<<<BATCH / 256, 256, 0, stream>>>(partial, out);
}

// Round 7
// 105.804 us; speedup vs baseline: 1.2654x; 1.2654x over previous
//
#include <hip/hip_runtime.h>

// SNN forward: T=128, B=8192, I=2, H=256, O=2
//  cur[t,b,h] = x[t,b,0]*W1[h,0] + x[t,b,1]*W1[h,1]
//  scan: reset = (mem>1); mem = 0.9*mem + cur - reset; spk = (mem>1)
//  out[b,o] = (mean of spk over last 10 t) dot W2[o,:]
//
// R17 = R16 with the launch-bounds spill fixed. Ladder (scan dispatch):
//   R10 scalar RH=8, 16 waves/CU ..... 51.4 us  busy 37.8  VALUBusy 73%
//   R11 pk-broadcast RH=8 ............ 51.5 us  (instr -1.6x, time flat ->
//        fp32-pipe-width-bound; pk = 4 cyc, buys issue slots only)
//   R12 fused threadfence reduce ..... 75.2 us  (fence poison; REVERTED)
//   R13 pk-PAIR RH=4, 32 waves/CU .... 59.2 us  busy 49.7  VALUBusy 84%
//   R15 pk-PAIR RH=8, 16 waves/CU .... 59.9 us  busy 48.0  (pk-PAIR
//        marshaling = +10 us busy vs scalar; REVERTED)
//   R16 scalar RH=4, lb(512,8) ....... 85 us    VGPR CLAMPED TO 32 -> SPILL
//        (WRITE 39 MB, FETCH 20 MB of scratch traffic; theory untested)
// Key structural fact: total waves = 128bg x (256/RH) -> RH=8 caps the
// grid at 16 waves/CU (50% occ); RH=4 supplies 32/CU, and R13 measured
// VALUBusy 84% there. Scalar RH=4 busy ~= 49.7 - 10.4 (pk-PAIR tax) ~= 39
// us -> ~46 us at 84% fill.
// THIS ROUND: lb(512, 4) -> 64-VGPR cap (empirical map: cap ~ 256/arg2;
// (512,8) gave 32 and spilled). Natural allocation ~44-52 fits, and since
// actual VGPR <= 64 the HW still co-resides 4 blocks/CU = 8 waves/SIMD
// (launch_bounds constrains the allocator, residency follows real VGPR).
//
// Epilogue bit-exactness (absmax must stay 0.0): R13/R16-verified scheme.
// Old tree: per-wave 8-term sequential __fadd_rn chain (ascending h), then
// (c0+c1)+(c2+c3) over 4 waves, then ascending-hg chain in snn_reduce.
// With RH=4 threads publish avg[h]=cnt/10 to LDS; wave0 rebuilds the EXACT
// chains: c_k = sequential 8-term chain over h_local=8k..8k+7,
// s = (c0+c1)+(c2+c3). partial layout + snn_reduce unchanged.
//
// Kept: saddr-form loads (t*BATCH wave-uniform SGPR base + fixed lane
// voffset, zero per-load VALU), PF=8 rotating register prefetch, XCD
// swizzle (bg=blockIdx&127, hg=blockIdx>>7), per-op fp32 rounding, no FMA.

#define T_STEPS 128
#define BATCH   8192
#define HID     256
#define TAIL    10
#define RH      4      // hidden chains per thread
#define LB      64     // batch rows per block (= lanes per wave)
#define NWAVE   8      // waves per block; block covers NWAVE*RH = 32 h
#define HG      8      // h-groups (HID / 32)
#define NBG     (BATCH / LB)   // 128 batch groups
#define PF      8      // prefetch depth (t-steps in flight)

__global__ __launch_bounds__(512, 4) void snn_scan(const float* __restrict__ x,
                                                   const float* __restrict__ W1,
                                                   const float* __restrict__ W2,
                                                   float2* __restrict__ partial) {
    const int tid   = threadIdx.x;
    const int lane  = tid & 63;
    const int wave  = tid >> 6;                // 0..7
    const int bg    = blockIdx.x & (NBG - 1);  // same bg -> same XCD for all hg
    const int hg    = blockIdx.x >> 7;         // 0..7
    const int b     = bg * LB + lane;          // batch row (lane part of addr)
    const int hbase = hg * (NWAVE * RH) + wave * RH;

    // W1 rows for my 4 h (wave-uniform addresses -> scalarized, one-time)
    float w0[RH], w1[RH];
#pragma unroll
    for (int r = 0; r < RH; ++r) {
        w0[r] = W1[2 * (hbase + r)];
        w1[r] = W1[2 * (hbase + r) + 1];
    }

    // Uniform-base addressing: xp + t*BATCH is wave-uniform (SGPR base,
    // SALU-stepped); + b is the fixed per-lane voffset.
    const float2* xp = (const float2*)x;

    float mem[RH], spk[RH], cnt[RH];
#pragma unroll
    for (int r = 0; r < RH; ++r) { mem[r] = 0.0f; spk[r] = 0.0f; cnt[r] = 0.0f; }

#define LOADX(t) xp[(size_t)(t) * BATCH + b]

    // R10's exact per-element op sequence (scalar, per-op rounding, no FMA):
#define STEP(r, xa, xc)                                                           \
    {                                                                             \
        const float c = __fadd_rn(__fmul_rn((xa), w0[r]), __fmul_rn((xc), w1[r]));\
        mem[r] = __fsub_rn(__fadd_rn(__fmul_rn(0.9f, mem[r]), c), spk[r]);        \
        spk[r] = (mem[r] > 1.0f) ? 1.0f : 0.0f;                                   \
    }

    // ---- warm-up: fill rotating prefetch buffer with t = 0..7 ----
    float2 buf[PF];
#pragma unroll
    for (int j = 0; j < PF; ++j) buf[j] = LOADX(j);

    // ---- main loop: t = 0..111 (14 iters), prefetch t+8 (<= 119) ----
    for (int tb = 0; tb < T_STEPS - 2 * PF; tb += PF) {
#pragma unroll
        for (int j = 0; j < PF; ++j) {
            const float2 xv = buf[j];
            buf[j] = LOADX(tb + PF + j);
#pragma unroll
            for (int r = 0; r < RH; ++r) STEP(r, xv.x, xv.y)
        }
    }

    // ---- t = 112..119: consume buf[j], refill with t = 120..127 ----
#pragma unroll
    for (int j = 0; j < PF; ++j) {
        const float2 xv = buf[j];
        buf[j] = LOADX(T_STEPS - PF + j);
#pragma unroll
        for (int r = 0; r < RH; ++r) {
            STEP(r, xv.x, xv.y)
            if (j >= PF - 2) cnt[r] += spk[r];   // t = 118, 119
        }
    }
    // ---- t = 120..127 (all counted) ----
#pragma unroll
    for (int j = 0; j < PF; ++j) {
        const float2 xv = buf[j];
#pragma unroll
        for (int r = 0; r < RH; ++r) {
            STEP(r, xv.x, xv.y)
            cnt[r] += spk[r];   // integer-valued, exact in fp32
        }
    }
#undef STEP
#undef LOADX

    // Publish per-h tail averages; wave0 rebuilds the exact R10 tree.
    __shared__ float avgs[NWAVE * RH][LB];    // 32 x 64 floats = 8 KB
#pragma unroll
    for (int r = 0; r < RH; ++r)
        avgs[wave * RH + r][lane] = cnt[r] / 10.0f;
    __syncthreads();

    if (wave == 0) {
        // c_k = sequential 8-term __fadd_rn chain over h_local = 8k..8k+7
        // (== old wave-k per-thread chain), then (c0+c1)+(c2+c3).
        float c0[4], c1[4];
#pragma unroll
        for (int k = 0; k < 4; ++k) {
            float s0 = 0.0f, s1 = 0.0f;
#pragma unroll
            for (int j = 0; j < 8; ++j) {
                const int hl = 8 * k + j;
                const float a = avgs[hl][lane];
                s0 = __fadd_rn(s0, __fmul_rn(a, W2[hg * 32 + hl]));
                s1 = __fadd_rn(s1, __fmul_rn(a, W2[HID + hg * 32 + hl]));
            }
            c0[k] = s0; c1[k] = s1;
        }
        float2 s;
        s.x = __fadd_rn(__fadd_rn(c0[0], c0[1]), __fadd_rn(c0[2], c0[3]));
        s.y = __fadd_rn(__fadd_rn(c1[0], c1[1]), __fadd_rn(c1[2], c1[3]));
        partial[(size_t)hg * BATCH + b] = s;
    }
}

// sum the 8 h-group partials -> out[b, 0:2] (ascending hg, exact chain)
__global__ __launch_bounds__(256) void snn_reduce(const float2* __restrict__ partial,
                                                  float2* __restrict__ out) {
    const int b = blockIdx.x * 256 + threadIdx.x;   // 8192 threads
    float sx = 0.0f, sy = 0.0f;
#pragma unroll
    for (int hg = 0; hg < HG; ++hg) {
        const float2 p = partial[(size_t)hg * BATCH + b];
        sx = __fadd_rn(sx, p.x);
        sy = __fadd_rn(sy, p.y);
    }
    out[b] = make_float2(sx, sy);
}

extern "C" void kernel_launch(void* const* d_in, const int* in_sizes, int n_in,
                              void* d_out, int out_size, void* d_ws, size_t ws_size,
                              hipStream_t stream) {
    const float* x  = (const float*)d_in[0];  // (128, 8192, 2)
    const float* W1 = (const float*)d_in[1];  // (256, 2)
    const float* W2 = (const float*)d_in[2];  // (2, 256)
    float2* out     = (float2*)d_out;         // (8192, 2)
    float2* partial = (float2*)d_ws;          // (8, 8192) float2 = 512 KB scratch

    snn_scan<<<NBG * HG, 512, 0, stream>>>(x, W1, W2, partial);
    snn_reduce<<<BATCH / 256, 256, 0, stream>>>(partial, out);
}

// Round 8
// 103.406 us; speedup vs baseline: 1.2948x; 1.0232x over previous
//
#include <hip/hip_runtime.h>

// SNN forward: T=128, B=8192, I=2, H=256, O=2
//  cur[t,b,h] = x[t,b,0]*W1[h,0] + x[t,b,1]*W1[h,1]
//  scan: reset = (mem>1); mem = 0.9*mem + cur - reset; spk = (mem>1)
//  out[b,o] = (mean of spk over last 10 t) dot W2[o,:]
//
// R18 = restore the measured optimum (R10 form). Final ladder:
//   R10 scalar RH=8, 16 w/CU ... 51.4 us  busy 37.8  VALU 73%   <- BEST
//   R11 pk-broadcast RH=8 ...... 51.5 us  (instr -1.6x, time flat:
//        fp32-pipe-WIDTH-bound; pk = 4 cyc = 2x scalar, conserves cycles)
//   R12 fused threadfence reduce 75.2 us  (device-fence L2 poison)
//   R13 pk-pair RH=4 ........... 59.2 us  busy 49.7  (pair-marshal +10us)
//   R15 pk-pair RH=8 ........... 59.9 us  busy 48.0  (same tax)
//   R16 scalar RH=4 lb(512,8) .. 85 us    (VGPR clamp 32 -> spill)
//   R17 scalar RH=4 lb(512,4) .. 54.6 us  busy 42.7  (per-t-per-wave fixed
//        overhead doubles with wave count; fill gain 73->78% can't pay)
// Conclusion: busy floor 37.8 us (chain ledger 27.3 + ~49 cyc/t/wave of
// load/copy/bookkeeping), best fill at that floor 73%. All encoding and
// occupancy axes measured-exhausted; 51.4 us is the structural limit of
// this op on gfx950 under bit-exactness (per-op rounding, no FMA, no MFMA).
//
// Structure: RH=8 chains/thread, 4 waves x 64 lanes, grid 1024 (128 bg x
// 8 hg); saddr-form loads (t*BATCH wave-uniform SGPR base, SALU-stepped,
// fixed lane voffset -> zero per-load VALU); PF=8 rotating register
// prefetch; XCD swizzle (bg=blockIdx&127 -> all 8 hg-sharers of one
// x-slice on one XCD); two-dispatch epilogue (partial -> snn_reduce).
//
// Numerics: per-op fp32 rounding (__fmul_rn/__fadd_rn/__fsub_rn, no FMA),
// op order + reduction order identical to all absmax-0.0 rounds.

#define T_STEPS 128
#define BATCH   8192
#define HID     256
#define TAIL    10
#define RH      8      // hidden chains per thread
#define LB      64     // batch rows per block (= lanes per wave)
#define NWAVE   4      // waves per block; block covers NWAVE*RH = 32 h
#define HG      8      // h-groups (HID / 32)
#define NBG     (BATCH / LB)   // 128 batch groups
#define PF      8      // prefetch depth (t-steps in flight)

__global__ __launch_bounds__(256) void snn_scan(const float* __restrict__ x,
                                                const float* __restrict__ W1,
                                                const float* __restrict__ W2,
                                                float2* __restrict__ partial) {
    const int tid   = threadIdx.x;
    const int lane  = tid & 63;
    const int wave  = tid >> 6;
    const int bg    = blockIdx.x & (NBG - 1);  // same bg -> same XCD for all hg
    const int hg    = blockIdx.x >> 7;
    const int b     = bg * LB + lane;          // batch row (lane part of addr)
    const int hbase = hg * (NWAVE * RH) + wave * RH;

    // W1 rows for my 8 h (wave-uniform addresses -> scalarized, one-time)
    float w0[RH], w1[RH];
#pragma unroll
    for (int r = 0; r < RH; ++r) {
        w0[r] = W1[2 * (hbase + r)];
        w1[r] = W1[2 * (hbase + r) + 1];
    }

    // Uniform-base addressing: xp + t*BATCH is wave-uniform (SGPR base,
    // SALU-stepped); + b is the fixed per-lane voffset.
    const float2* xp = (const float2*)x;

    float mem[RH], spk[RH], cnt[RH];
#pragma unroll
    for (int r = 0; r < RH; ++r) { mem[r] = 0.0f; spk[r] = 0.0f; cnt[r] = 0.0f; }

#define LOADX(t) xp[(size_t)(t) * BATCH + b]

#define STEP(r, xa, xc)                                                           \
    {                                                                             \
        const float c = __fadd_rn(__fmul_rn((xa), w0[r]), __fmul_rn((xc), w1[r]));\
        mem[r] = __fsub_rn(__fadd_rn(__fmul_rn(0.9f, mem[r]), c), spk[r]);        \
        spk[r] = (mem[r] > 1.0f) ? 1.0f : 0.0f;                                   \
    }

    // ---- warm-up: fill rotating prefetch buffer with t = 0..7 ----
    float2 buf[PF];
#pragma unroll
    for (int j = 0; j < PF; ++j) buf[j] = LOADX(j);

    // ---- main loop: t = 0..111 (14 iters), prefetch t+8 (<= 119) ----
    for (int tb = 0; tb < T_STEPS - 2 * PF; tb += PF) {
#pragma unroll
        for (int j = 0; j < PF; ++j) {
            const float2 xv = buf[j];
            buf[j] = LOADX(tb + PF + j);
#pragma unroll
            for (int r = 0; r < RH; ++r) STEP(r, xv.x, xv.y)
        }
    }

    // ---- t = 112..119: consume buf[j], refill with t = 120..127 ----
#pragma unroll
    for (int j = 0; j < PF; ++j) {
        const float2 xv = buf[j];
        buf[j] = LOADX(T_STEPS - PF + j);
#pragma unroll
        for (int r = 0; r < RH; ++r) {
            STEP(r, xv.x, xv.y)
            if (j >= PF - 2) cnt[r] += spk[r];   // t = 118, 119
        }
    }
    // ---- t = 120..127 (all counted) ----
#pragma unroll
    for (int j = 0; j < PF; ++j) {
        const float2 xv = buf[j];
#pragma unroll
        for (int r = 0; r < RH; ++r) {
            STEP(r, xv.x, xv.y)
            cnt[r] += spk[r];   // integer-valued, exact in fp32
        }
    }
#undef STEP
#undef LOADX

    // per-thread partial of out[b, :] over my 8 h (ascending h order)
    float p0 = 0.0f, p1 = 0.0f;
#pragma unroll
    for (int r = 0; r < RH; ++r) {
        const float avg = cnt[r] / 10.0f;
        p0 = __fadd_rn(p0, __fmul_rn(avg, W2[hbase + r]));
        p1 = __fadd_rn(p1, __fmul_rn(avg, W2[HID + hbase + r]));
    }

    // combine the block's 4 waves (different h-chunks, same b per lane)
    __shared__ float2 red[NWAVE][LB];
    red[wave][lane] = make_float2(p0, p1);
    __syncthreads();
    if (wave == 0) {
        const float2 a0 = red[0][lane], a1 = red[1][lane];
        const float2 a2 = red[2][lane], a3 = red[3][lane];
        float2 s;
        s.x = __fadd_rn(__fadd_rn(a0.x, a1.x), __fadd_rn(a2.x, a3.x));
        s.y = __fadd_rn(__fadd_rn(a0.y, a1.y), __fadd_rn(a2.y, a3.y));
        partial[(size_t)hg * BATCH + b] = s;
    }
}

// sum the 8 h-group partials -> out[b, 0:2] (ascending hg, exact chain)
__global__ __launch_bounds__(256) void snn_reduce(const float2* __restrict__ partial,
                                                  float2* __restrict__ out) {
    const int b = blockIdx.x * 256 + threadIdx.x;   // 8192 threads
    float sx = 0.0f, sy = 0.0f;
#pragma unroll
    for (int hg = 0; hg < HG; ++hg) {
        const float2 p = partial[(size_t)hg * BATCH + b];
        sx = __fadd_rn(sx, p.x);
        sy = __fadd_rn(sy, p.y);
    }
    out[b] = make_float2(sx, sy);
}

extern "C" void kernel_launch(void* const* d_in, const int* in_sizes, int n_in,
                              void* d_out, int out_size, void* d_ws, size_t ws_size,
                              hipStream_t stream) {
    const float* x  = (const float*)d_in[0];  // (128, 8192, 2)
    const float* W1 = (const float*)d_in[1];  // (256, 2)
    const float* W2 = (const float*)d_in[2];  // (2, 256)
    float2* out     = (float2*)d_out;         // (8192, 2)
    float2* partial = (float2*)d_ws;          // (8, 8192) float2 = 512 KB scratch

    snn_scan<<<NBG * HG, 256, 0, stream>>>(x, W1, W2, partial);
    snn_reduce<<<BATCH / 256, 256, 0, stream>>>(partial, out);
}